// Round 10
// baseline (435.175 us; speedup 1.0000x reference)
//
#include <hip/hip_runtime.h>
#include <hip/hip_bf16.h>

#define S_STEPS 64

typedef __bf16 bf16x8 __attribute__((ext_vector_type(8)));
typedef float  f32x4  __attribute__((ext_vector_type(4)));

// ---- async 16B global->LDS (wave-uniform base + lane*16 contiguous dest) ----
__device__ __forceinline__ void async16(const void* g, void* l) {
    __builtin_amdgcn_global_load_lds((const __attribute__((address_space(1))) void*)g,
                                     (__attribute__((address_space(3))) void*)l,
                                     16, 0, 0);
}

// ---------------- encoder (T-parallel) — R9 verbatim ----------------
__global__ void snn_encoder_tp(const float4* __restrict__ xv, ushort4* __restrict__ r,
                               int B, int T, int F4) {
    const int f4i = threadIdx.x & 63;
    const int tc  = threadIdx.x >> 6;           // 0..3
    const int b   = blockIdx.y;
    const int f4  = blockIdx.x * 64 + f4i;
    __shared__ int4 red[4][64];

    int c0 = 0, c1 = 0, c2 = 0, c3 = 0;
    if (b > 0) {
        const float4* xb = xv + ((size_t)b * T + tc * 32) * F4 + f4;
        const float4* xp = xb - (size_t)T * F4;
        for (int t = 0; t < 32; ++t) {
            float4 a = xb[(size_t)t * F4];
            float4 p = xp[(size_t)t * F4];
            c0 += (__fsub_rn(a.x, p.x) >= 0.2f) ? 1 : 0;
            c1 += (__fsub_rn(a.y, p.y) >= 0.2f) ? 1 : 0;
            c2 += (__fsub_rn(a.z, p.z) >= 0.2f) ? 1 : 0;
            c3 += (__fsub_rn(a.w, p.w) >= 0.2f) ? 1 : 0;
        }
    }
    red[tc][f4i] = int4{c0, c1, c2, c3};
    __syncthreads();
    if (tc == 0) {
        int4 a = red[0][f4i], bb = red[1][f4i], cc = red[2][f4i], dd = red[3][f4i];
        int s0 = a.x + bb.x + cc.x + dd.x;
        int s1 = a.y + bb.y + cc.y + dd.y;
        int s2 = a.z + bb.z + cc.z + dd.z;
        int s3 = a.w + bb.w + cc.w + dd.w;
        ushort4 o;
        o.x = __hip_bfloat16_raw(__float2bfloat16((float)s0 * (1.0f / 128.0f))).x;
        o.y = __hip_bfloat16_raw(__float2bfloat16((float)s1 * (1.0f / 128.0f))).x;
        o.z = __hip_bfloat16_raw(__float2bfloat16((float)s2 * (1.0f / 128.0f))).x;
        o.w = __hip_bfloat16_raw(__float2bfloat16((float)s3 * (1.0f / 128.0f))).x;
        r[(size_t)b * F4 + f4] = o;
    }
}

// ---------------- batched 3-way bf16 split (vec4) — R9 verbatim ----------------
__global__ void split_w3_v4(const float4* __restrict__ Wa, const float4* __restrict__ Wb,
                            const float4* __restrict__ Wc, int na4, int nb4, int nc4,
                            ushort4* __restrict__ outA,
                            ushort4* __restrict__ outB,
                            ushort4* __restrict__ outC) {
    int i = blockIdx.x * blockDim.x + threadIdx.x;
    const float4* W; ushort4* out; int n4; int j = i;
    if (j < na4)             { W = Wa; out = outA; n4 = na4; }
    else if ((j -= na4) < nb4) { W = Wb; out = outB; n4 = nb4; }
    else if ((j -= nb4) < nc4) { W = Wc; out = outC; n4 = nc4; }
    else return;
    float4 w = W[j];
    float wv[4] = {w.x, w.y, w.z, w.w};
    unsigned short hv[4], mv[4], lv[4];
    #pragma unroll
    for (int q = 0; q < 4; ++q) {
        __hip_bfloat16 hh = __float2bfloat16(wv[q]);
        float r1 = __fsub_rn(wv[q], __bfloat162float(hh));   // exact
        __hip_bfloat16 mm = __float2bfloat16(r1);
        float r2 = __fsub_rn(r1, __bfloat162float(mm));      // exact
        hv[q] = __hip_bfloat16_raw(hh).x;
        mv[q] = __hip_bfloat16_raw(mm).x;
        lv[q] = __hip_bfloat16_raw(__float2bfloat16(r2)).x;
    }
    out[j]          = ushort4{hv[0], hv[1], hv[2], hv[3]};
    out[j + n4]     = ushort4{mv[0], mv[1], mv[2], mv[3]};
    out[j + 2 * n4] = ushort4{lv[0], lv[1], lv[2], lv[3]};
}

// ================= GEMM variant A: block 128x256, per-wave 64x128 =================
// R9 structure + chunk-major LDS staging: per 16-row group, lane fetches global
// row (lane&15), k-chunk (lane>>4); LDS element (grp,r,c) at 512*grp+128*c+8*r shorts.
// Frag reads become a linear 16B/lane sweep -> zero bank conflicts.
__global__ __launch_bounds__(256, 2)
void snn_gemm_mfma_w(const __hip_bfloat16* __restrict__ A,
                     const __hip_bfloat16* __restrict__ Whi,
                     const __hip_bfloat16* __restrict__ Wmid,
                     const __hip_bfloat16* __restrict__ Wlo,
                     const float* __restrict__ bias,
                     float* __restrict__ C,
                     int M, int N, int K) {
    __shared__ __align__(16) unsigned short As[128 * 32];   // 8 KB  (8 groups)
    __shared__ __align__(16) unsigned short Bs[256 * 32];   // 16 KB (16 groups)
    const int t    = threadIdx.x;
    const int wave = t >> 6;
    const int lane = t & 63;

    int m_idx, n_idx;
    {
        int gx = gridDim.x, gy = gridDim.y;
        int flat = blockIdx.y * gx + blockIdx.x;
        if ((gy & 7) == 0) {
            int x = flat & 7, local = flat >> 3, h = gy >> 3;
            m_idx = x * h + (local % h);
            n_idx = local / h;
        } else { m_idx = blockIdx.y; n_idx = blockIdx.x; }
    }
    const int m0 = m_idx * 128;
    const int n0 = n_idx * 256;
    const int wm = (wave >> 1) * 64;
    const int wn = (wave & 1) * 128;

    // staging: per 16-row group, lane -> (row = lane&15, chunk = lane>>4)
    const int gr = lane & 15;
    const int gc = (lane >> 4) * 8;          // k-offset in shorts
    // frag read: linear sweep within group
    const int foff = ((lane >> 4) * 16 + (lane & 15)) * 8;   // shorts

    f32x4 acc[4][8] = {};

    const __hip_bfloat16* parts[3] = {Whi, Wmid, Wlo};
    for (int part = 0; part < 3; ++part) {
        const __hip_bfloat16* Bw = parts[part];
        for (int k0 = 0; k0 < K; k0 += 32) {
            __syncthreads();
            #pragma unroll
            for (int q = 0; q < 2; ++q) {
                int grp = wave * 2 + q;      // A groups 0..7
                async16(A + (size_t)(m0 + grp * 16 + gr) * K + k0 + gc,
                        &As[grp * 512 + lane * 8]);
            }
            #pragma unroll
            for (int q = 0; q < 4; ++q) {
                int grp = wave * 4 + q;      // B groups 0..15
                async16(Bw + (size_t)(n0 + grp * 16 + gr) * K + k0 + gc,
                        &Bs[grp * 512 + lane * 8]);
            }
            __syncthreads();

            bf16x8 af[4], bfr[8];
            #pragma unroll
            for (int i = 0; i < 4; ++i)
                af[i] = *(const bf16x8*)&As[((wm >> 4) + i) * 512 + foff];
            #pragma unroll
            for (int j = 0; j < 8; ++j)
                bfr[j] = *(const bf16x8*)&Bs[((wn >> 4) + j) * 512 + foff];

            #pragma unroll
            for (int i = 0; i < 4; ++i)
                #pragma unroll
                for (int j = 0; j < 8; ++j)
                    acc[i][j] = __builtin_amdgcn_mfma_f32_16x16x32_bf16(af[i], bfr[j], acc[i][j], 0, 0, 0);
        }
    }

    #pragma unroll
    for (int i = 0; i < 4; ++i) {
        int mg = m0 + wm + i * 16 + (lane >> 4) * 4;
        #pragma unroll
        for (int j = 0; j < 8; ++j) {
            int ng = n0 + wn + j * 16 + (lane & 15);
            float bb = bias[ng];
            #pragma unroll
            for (int r = 0; r < 4; ++r)
                C[(size_t)(mg + r) * N + ng] = acc[i][j][r] + bb;
        }
    }
}

// ================= GEMM variant B: block 128x128, per-wave 64x64 =================
// Same chunk-major staging/reads as variant A.
__global__ __launch_bounds__(256)
void snn_gemm_mfma_n(const __hip_bfloat16* __restrict__ A,
                     const __hip_bfloat16* __restrict__ Whi,
                     const __hip_bfloat16* __restrict__ Wmid,
                     const __hip_bfloat16* __restrict__ Wlo,
                     const float* __restrict__ bias,
                     float* __restrict__ C,
                     int M, int N, int K) {
    __shared__ __align__(16) unsigned short As[128 * 32];   // 8 groups
    __shared__ __align__(16) unsigned short Bs[128 * 32];   // 8 groups
    const int t    = threadIdx.x;
    const int wave = t >> 6;
    const int lane = t & 63;

    int m_idx, n_idx;
    {
        int gx = gridDim.x, gy = gridDim.y;
        int flat = blockIdx.y * gx + blockIdx.x;
        if ((gy & 7) == 0) {
            int x = flat & 7, local = flat >> 3, h = gy >> 3;
            m_idx = x * h + (local % h);
            n_idx = local / h;
        } else { m_idx = blockIdx.y; n_idx = blockIdx.x; }
    }
    const int m0 = m_idx * 128;
    const int n0 = n_idx * 128;
    const int wm = (wave & 1) * 64;
    const int wn = (wave >> 1) * 64;

    const int gr = lane & 15;
    const int gc = (lane >> 4) * 8;
    const int foff = ((lane >> 4) * 16 + (lane & 15)) * 8;

    f32x4 acc[4][4] = {};

    const __hip_bfloat16* parts[3] = {Whi, Wmid, Wlo};
    for (int part = 0; part < 3; ++part) {
        const __hip_bfloat16* Bw = parts[part];
        for (int k0 = 0; k0 < K; k0 += 32) {
            __syncthreads();
            #pragma unroll
            for (int q = 0; q < 2; ++q) {
                int grp = wave * 2 + q;      // groups 0..7
                async16(A  + (size_t)(m0 + grp * 16 + gr) * K + k0 + gc,
                        &As[grp * 512 + lane * 8]);
                async16(Bw + (size_t)(n0 + grp * 16 + gr) * K + k0 + gc,
                        &Bs[grp * 512 + lane * 8]);
            }
            __syncthreads();

            bf16x8 af[4], bfr[4];
            #pragma unroll
            for (int i = 0; i < 4; ++i) {
                af[i]  = *(const bf16x8*)&As[((wm >> 4) + i) * 512 + foff];
                bfr[i] = *(const bf16x8*)&Bs[((wn >> 4) + i) * 512 + foff];
            }
            #pragma unroll
            for (int i = 0; i < 4; ++i)
                #pragma unroll
                for (int j = 0; j < 4; ++j)
                    acc[i][j] = __builtin_amdgcn_mfma_f32_16x16x32_bf16(af[i], bfr[j], acc[i][j], 0, 0, 0);
        }
    }

    #pragma unroll
    for (int i = 0; i < 4; ++i) {
        int mg = m0 + wm + i * 16 + (lane >> 4) * 4;
        #pragma unroll
        for (int j = 0; j < 4; ++j) {
            int ng = n0 + wn + j * 16 + (lane & 15);
            float bb = bias[ng];
            #pragma unroll
            for (int r = 0; r < 4; ++r)
                C[(size_t)(mg + r) * N + ng] = acc[i][j][r] + bb;
        }
    }
}

// ---------------- LIF scans — R9 verbatim ----------------
__global__ void snn_lif_bf16_v4(const float4* __restrict__ cur, ushort4* __restrict__ spk,
                                int BH4, int bcast) {
    int idx = blockIdx.x * blockDim.x + threadIdx.x;
    if (idx >= BH4) return;
    float m0 = 0.0f, m1 = 0.0f, m2 = 0.0f, m3 = 0.0f;
    const unsigned short one = __hip_bfloat16_raw(__float2bfloat16(1.0f)).x;
    if (bcast) {
        float4 c = cur[idx];
        for (int s = 0; s < S_STEPS; ++s) {
            float r0 = (m0 > 1.0f) ? 1.0f : 0.0f;
            float r1 = (m1 > 1.0f) ? 1.0f : 0.0f;
            float r2 = (m2 > 1.0f) ? 1.0f : 0.0f;
            float r3 = (m3 > 1.0f) ? 1.0f : 0.0f;
            m0 = __fsub_rn(__fadd_rn(__fmul_rn(0.9f, m0), c.x), r0);
            m1 = __fsub_rn(__fadd_rn(__fmul_rn(0.9f, m1), c.y), r1);
            m2 = __fsub_rn(__fadd_rn(__fmul_rn(0.9f, m2), c.z), r2);
            m3 = __fsub_rn(__fadd_rn(__fmul_rn(0.9f, m3), c.w), r3);
            ushort4 o;
            o.x = (m0 > 1.0f) ? one : (unsigned short)0;
            o.y = (m1 > 1.0f) ? one : (unsigned short)0;
            o.z = (m2 > 1.0f) ? one : (unsigned short)0;
            o.w = (m3 > 1.0f) ? one : (unsigned short)0;
            spk[(size_t)s * BH4 + idx] = o;
        }
    } else {
        for (int s0 = 0; s0 < S_STEPS; s0 += 4) {
            float4 c[4];
            #pragma unroll
            for (int u = 0; u < 4; ++u)
                c[u] = cur[(size_t)(s0 + u) * BH4 + idx];   // 4 loads in flight
            #pragma unroll
            for (int u = 0; u < 4; ++u) {
                float r0 = (m0 > 1.0f) ? 1.0f : 0.0f;
                float r1 = (m1 > 1.0f) ? 1.0f : 0.0f;
                float r2 = (m2 > 1.0f) ? 1.0f : 0.0f;
                float r3 = (m3 > 1.0f) ? 1.0f : 0.0f;
                m0 = __fsub_rn(__fadd_rn(__fmul_rn(0.9f, m0), c[u].x), r0);
                m1 = __fsub_rn(__fadd_rn(__fmul_rn(0.9f, m1), c[u].y), r1);
                m2 = __fsub_rn(__fadd_rn(__fmul_rn(0.9f, m2), c[u].z), r2);
                m3 = __fsub_rn(__fadd_rn(__fmul_rn(0.9f, m3), c[u].w), r3);
                ushort4 o;
                o.x = (m0 > 1.0f) ? one : (unsigned short)0;
                o.y = (m1 > 1.0f) ? one : (unsigned short)0;
                o.z = (m2 > 1.0f) ? one : (unsigned short)0;
                o.w = (m3 > 1.0f) ? one : (unsigned short)0;
                spk[(size_t)(s0 + u) * BH4 + idx] = o;
            }
        }
    }
}

__global__ void snn_lif_f32_v4(const float4* __restrict__ cur, float4* __restrict__ spk, int BH4) {
    int idx = blockIdx.x * blockDim.x + threadIdx.x;
    if (idx >= BH4) return;
    float m0 = 0.0f, m1 = 0.0f, m2 = 0.0f, m3 = 0.0f;
    for (int s0 = 0; s0 < S_STEPS; s0 += 4) {
        float4 c[4];
        #pragma unroll
        for (int u = 0; u < 4; ++u)
            c[u] = cur[(size_t)(s0 + u) * BH4 + idx];       // 4 loads in flight
        #pragma unroll
        for (int u = 0; u < 4; ++u) {
            float r0 = (m0 > 1.0f) ? 1.0f : 0.0f;
            float r1 = (m1 > 1.0f) ? 1.0f : 0.0f;
            float r2 = (m2 > 1.0f) ? 1.0f : 0.0f;
            float r3 = (m3 > 1.0f) ? 1.0f : 0.0f;
            m0 = __fsub_rn(__fadd_rn(__fmul_rn(0.9f, m0), c[u].x), r0);
            m1 = __fsub_rn(__fadd_rn(__fmul_rn(0.9f, m1), c[u].y), r1);
            m2 = __fsub_rn(__fadd_rn(__fmul_rn(0.9f, m2), c[u].z), r2);
            m3 = __fsub_rn(__fadd_rn(__fmul_rn(0.9f, m3), c[u].w), r3);
            float4 o;
            o.x = (m0 > 1.0f) ? 1.0f : 0.0f;
            o.y = (m1 > 1.0f) ? 1.0f : 0.0f;
            o.z = (m2 > 1.0f) ? 1.0f : 0.0f;
            o.w = (m3 > 1.0f) ? 1.0f : 0.0f;
            spk[(size_t)(s0 + u) * BH4 + idx] = o;
        }
    }
}

extern "C" void kernel_launch(void* const* d_in, const int* in_sizes, int n_in,
                              void* d_out, int out_size, void* d_ws, size_t ws_size,
                              hipStream_t stream) {
    const float* x  = (const float*)d_in[0];
    const float* W0 = (const float*)d_in[1];
    const float* b0 = (const float*)d_in[2];
    const float* W1 = (const float*)d_in[3];
    const float* b1 = (const float*)d_in[4];
    const float* W2 = (const float*)d_in[5];
    const float* b2 = (const float*)d_in[6];

    const int B = 256, T = 128, F = 512, H1 = 1024, H2 = 1024, H3 = 512;
    const int SB = S_STEPS * B;            // 16384

    // ---- workspace carve-up, all 16B aligned; total ~115 MB ----
    char* w = (char*)d_ws;
    __hip_bfloat16* spkA = (__hip_bfloat16*)w;              w += (size_t)SB * H1 * 2;   // 33.5 MB
    float*          curB = (float*)w;                       w += (size_t)SB * H1 * 4;   // 67 MB
    __hip_bfloat16* r_bf = (__hip_bfloat16*)w;              w += (size_t)B * F * 2;     // 256 KB
    float*          cur0 = (float*)w;                       w += (size_t)B * H1 * 4;    // 1 MB
    __hip_bfloat16* W0s  = (__hip_bfloat16*)w;              w += (size_t)3 * H1 * F * 2;
    __hip_bfloat16* W1s  = (__hip_bfloat16*)w;              w += (size_t)3 * H2 * H1 * 2;
    __hip_bfloat16* W2s  = (__hip_bfloat16*)w;              w += (size_t)3 * H3 * H2 * 2;

    const int nW0 = H1 * F, nW1 = H2 * H1, nW2 = H3 * H2;

    // batched weight splits, vec4
    {
        int n4 = (nW0 + nW1 + nW2) / 4;
        split_w3_v4<<<dim3((n4 + 255) / 256), dim3(256), 0, stream>>>(
            (const float4*)W0, (const float4*)W1, (const float4*)W2,
            nW0 / 4, nW1 / 4, nW2 / 4,
            (ushort4*)W0s, (ushort4*)W1s, (ushort4*)W2s);
    }

    // 1. delta encoder (T-parallel, 512 blocks) -> exact bf16 rates [B, F]
    snn_encoder_tp<<<dim3(F / 4 / 64, B), dim3(256), 0, stream>>>(
        (const float4*)x, (ushort4*)r_bf, B, T, F / 4);

    // 2. cur0 = r @ W0^T + b0   [256 x 1024, K=512]
    snn_gemm_mfma_n<<<dim3(H1 / 128, B / 128), dim3(256), 0, stream>>>(
        r_bf, W0s, W0s + nW0, W0s + 2 * nW0, b0, cur0, B, H1, F);

    // 3. LIF layer 0 (broadcast) -> spk0 bf16 [S, B*H1]
    snn_lif_bf16_v4<<<dim3(B * H1 / 4 / 256), dim3(256), 0, stream>>>(
        (const float4*)cur0, (ushort4*)spkA, B * H1 / 4, 1);

    // 4. cur1 = spk0 @ W1^T + b1   [16384 x 1024, K=1024]
    snn_gemm_mfma_w<<<dim3(H2 / 256, SB / 128), dim3(256), 0, stream>>>(
        spkA, W1s, W1s + nW1, W1s + 2 * nW1, b1, curB, SB, H2, H1);

    // 5. LIF layer 1 (unrolled) -> spk1 bf16 (reuse spkA)
    snn_lif_bf16_v4<<<dim3(B * H2 / 4 / 256), dim3(256), 0, stream>>>(
        (const float4*)curB, (ushort4*)spkA, B * H2 / 4, 0);

    // 6. cur2 = spk1 @ W2^T + b2   [16384 x 512, K=1024]
    snn_gemm_mfma_n<<<dim3(H3 / 128, SB / 128), dim3(256), 0, stream>>>(
        spkA, W2s, W2s + nW2, W2s + 2 * nW2, b2, curB, SB, H3, H2);

    // 7. LIF layer 2 (unrolled) -> d_out fp32 [S, B*H3]
    snn_lif_f32_v4<<<dim3(B * H3 / 4 / 256), dim3(256), 0, stream>>>(
        (const float4*)curB, (float4*)d_out, B * H3 / 4);
}

// Round 11
// 359.777 us; speedup vs baseline: 1.2096x; 1.2096x over previous
//
#include <hip/hip_runtime.h>
#include <hip/hip_bf16.h>

#define S_STEPS 64

typedef __bf16 bf16x8 __attribute__((ext_vector_type(8)));
typedef float  f32x4  __attribute__((ext_vector_type(4)));

// ---- async 16B global->LDS (wave-uniform base + lane*16 contiguous dest) ----
__device__ __forceinline__ void async16(const void* g, void* l) {
    __builtin_amdgcn_global_load_lds((const __attribute__((address_space(1))) void*)g,
                                     (__attribute__((address_space(3))) void*)l,
                                     16, 0, 0);
}

// ---------------- encoder (T-parallel) — R9 verbatim ----------------
__global__ void snn_encoder_tp(const float4* __restrict__ xv, ushort4* __restrict__ r,
                               int B, int T, int F4) {
    const int f4i = threadIdx.x & 63;
    const int tc  = threadIdx.x >> 6;           // 0..3
    const int b   = blockIdx.y;
    const int f4  = blockIdx.x * 64 + f4i;
    __shared__ int4 red[4][64];

    int c0 = 0, c1 = 0, c2 = 0, c3 = 0;
    if (b > 0) {
        const float4* xb = xv + ((size_t)b * T + tc * 32) * F4 + f4;
        const float4* xp = xb - (size_t)T * F4;
        for (int t = 0; t < 32; ++t) {
            float4 a = xb[(size_t)t * F4];
            float4 p = xp[(size_t)t * F4];
            c0 += (__fsub_rn(a.x, p.x) >= 0.2f) ? 1 : 0;
            c1 += (__fsub_rn(a.y, p.y) >= 0.2f) ? 1 : 0;
            c2 += (__fsub_rn(a.z, p.z) >= 0.2f) ? 1 : 0;
            c3 += (__fsub_rn(a.w, p.w) >= 0.2f) ? 1 : 0;
        }
    }
    red[tc][f4i] = int4{c0, c1, c2, c3};
    __syncthreads();
    if (tc == 0) {
        int4 a = red[0][f4i], bb = red[1][f4i], cc = red[2][f4i], dd = red[3][f4i];
        int s0 = a.x + bb.x + cc.x + dd.x;
        int s1 = a.y + bb.y + cc.y + dd.y;
        int s2 = a.z + bb.z + cc.z + dd.z;
        int s3 = a.w + bb.w + cc.w + dd.w;
        ushort4 o;
        o.x = __hip_bfloat16_raw(__float2bfloat16((float)s0 * (1.0f / 128.0f))).x;
        o.y = __hip_bfloat16_raw(__float2bfloat16((float)s1 * (1.0f / 128.0f))).x;
        o.z = __hip_bfloat16_raw(__float2bfloat16((float)s2 * (1.0f / 128.0f))).x;
        o.w = __hip_bfloat16_raw(__float2bfloat16((float)s3 * (1.0f / 128.0f))).x;
        r[(size_t)b * F4 + f4] = o;
    }
}

// ---------------- batched 3-way bf16 split (vec4) — R9 verbatim ----------------
__global__ void split_w3_v4(const float4* __restrict__ Wa, const float4* __restrict__ Wb,
                            const float4* __restrict__ Wc, int na4, int nb4, int nc4,
                            ushort4* __restrict__ outA,
                            ushort4* __restrict__ outB,
                            ushort4* __restrict__ outC) {
    int i = blockIdx.x * blockDim.x + threadIdx.x;
    const float4* W; ushort4* out; int n4; int j = i;
    if (j < na4)             { W = Wa; out = outA; n4 = na4; }
    else if ((j -= na4) < nb4) { W = Wb; out = outB; n4 = nb4; }
    else if ((j -= nb4) < nc4) { W = Wc; out = outC; n4 = nc4; }
    else return;
    float4 w = W[j];
    float wv[4] = {w.x, w.y, w.z, w.w};
    unsigned short hv[4], mv[4], lv[4];
    #pragma unroll
    for (int q = 0; q < 4; ++q) {
        __hip_bfloat16 hh = __float2bfloat16(wv[q]);
        float r1 = __fsub_rn(wv[q], __bfloat162float(hh));   // exact
        __hip_bfloat16 mm = __float2bfloat16(r1);
        float r2 = __fsub_rn(r1, __bfloat162float(mm));      // exact
        hv[q] = __hip_bfloat16_raw(hh).x;
        mv[q] = __hip_bfloat16_raw(mm).x;
        lv[q] = __hip_bfloat16_raw(__float2bfloat16(r2)).x;
    }
    out[j]          = ushort4{hv[0], hv[1], hv[2], hv[3]};
    out[j + n4]     = ushort4{mv[0], mv[1], mv[2], mv[3]};
    out[j + 2 * n4] = ushort4{lv[0], lv[1], lv[2], lv[3]};
}

// Swizzled staging map (per 16-row x 32-col group = 64 slots x 16B):
//   slot s holds global (row = s>>2, chunk = ((s&3)+(s>>2)+(s>>4)) & 3)
//   -> lanes 4r..4r+3 read one contiguous 64B row segment (coalesced, = R9)
//   -> frag read slot(rho,kap) = 4*rho + ((kap - rho - (rho>>2)) & 3): all 8
//      four-bank groups hit once per 8-lane run (2-way per 16 lanes = free, m136)

// ================= GEMM variant A: block 128x256, per-wave 64x128 =================
__global__ __launch_bounds__(256, 2)
void snn_gemm_mfma_w(const __hip_bfloat16* __restrict__ A,
                     const __hip_bfloat16* __restrict__ Whi,
                     const __hip_bfloat16* __restrict__ Wmid,
                     const __hip_bfloat16* __restrict__ Wlo,
                     const float* __restrict__ bias,
                     float* __restrict__ C,
                     int M, int N, int K) {
    __shared__ __align__(16) unsigned short As[128 * 32];   // 8 groups
    __shared__ __align__(16) unsigned short Bs[256 * 32];   // 16 groups
    const int t    = threadIdx.x;
    const int wave = t >> 6;
    const int lane = t & 63;

    int m_idx, n_idx;
    {
        int gx = gridDim.x, gy = gridDim.y;
        int flat = blockIdx.y * gx + blockIdx.x;
        if ((gy & 7) == 0) {
            int x = flat & 7, local = flat >> 3, h = gy >> 3;
            m_idx = x * h + (local % h);
            n_idx = local / h;
        } else { m_idx = blockIdx.y; n_idx = blockIdx.x; }
    }
    const int m0 = m_idx * 128;
    const int n0 = n_idx * 256;
    const int wm = (wave >> 1) * 64;
    const int wn = (wave & 1) * 128;

    // staging: slot = lane; row = lane>>2, swizzled chunk
    const int srow = lane >> 2;
    const int schk = ((lane & 3) + (lane >> 2) + (lane >> 4)) & 3;
    // frag read: slot for (rho, kap)
    const int rho  = lane & 15;
    const int kap  = lane >> 4;
    const int foff = ((rho << 2) + ((kap - rho - (rho >> 2)) & 3)) * 8;   // shorts

    f32x4 acc[4][8] = {};

    const __hip_bfloat16* parts[3] = {Whi, Wmid, Wlo};
    for (int part = 0; part < 3; ++part) {
        const __hip_bfloat16* Bw = parts[part];
        for (int k0 = 0; k0 < K; k0 += 32) {
            __syncthreads();
            #pragma unroll
            for (int q = 0; q < 2; ++q) {
                int grp = wave * 2 + q;      // A groups 0..7
                async16(A + (size_t)(m0 + grp * 16 + srow) * K + k0 + schk * 8,
                        &As[grp * 512 + lane * 8]);
            }
            #pragma unroll
            for (int q = 0; q < 4; ++q) {
                int grp = wave * 4 + q;      // B groups 0..15
                async16(Bw + (size_t)(n0 + grp * 16 + srow) * K + k0 + schk * 8,
                        &Bs[grp * 512 + lane * 8]);
            }
            __syncthreads();

            bf16x8 af[4], bfr[8];
            #pragma unroll
            for (int i = 0; i < 4; ++i)
                af[i] = *(const bf16x8*)&As[((wm >> 4) + i) * 512 + foff];
            #pragma unroll
            for (int j = 0; j < 8; ++j)
                bfr[j] = *(const bf16x8*)&Bs[((wn >> 4) + j) * 512 + foff];

            #pragma unroll
            for (int i = 0; i < 4; ++i)
                #pragma unroll
                for (int j = 0; j < 8; ++j)
                    acc[i][j] = __builtin_amdgcn_mfma_f32_16x16x32_bf16(af[i], bfr[j], acc[i][j], 0, 0, 0);
        }
    }

    #pragma unroll
    for (int i = 0; i < 4; ++i) {
        int mg = m0 + wm + i * 16 + (lane >> 4) * 4;
        #pragma unroll
        for (int j = 0; j < 8; ++j) {
            int ng = n0 + wn + j * 16 + (lane & 15);
            float bb = bias[ng];
            #pragma unroll
            for (int r = 0; r < 4; ++r)
                C[(size_t)(mg + r) * N + ng] = acc[i][j][r] + bb;
        }
    }
}

// ================= GEMM variant B: block 128x128, per-wave 64x64 =================
__global__ __launch_bounds__(256)
void snn_gemm_mfma_n(const __hip_bfloat16* __restrict__ A,
                     const __hip_bfloat16* __restrict__ Whi,
                     const __hip_bfloat16* __restrict__ Wmid,
                     const __hip_bfloat16* __restrict__ Wlo,
                     const float* __restrict__ bias,
                     float* __restrict__ C,
                     int M, int N, int K) {
    __shared__ __align__(16) unsigned short As[128 * 32];   // 8 groups
    __shared__ __align__(16) unsigned short Bs[128 * 32];   // 8 groups
    const int t    = threadIdx.x;
    const int wave = t >> 6;
    const int lane = t & 63;

    int m_idx, n_idx;
    {
        int gx = gridDim.x, gy = gridDim.y;
        int flat = blockIdx.y * gx + blockIdx.x;
        if ((gy & 7) == 0) {
            int x = flat & 7, local = flat >> 3, h = gy >> 3;
            m_idx = x * h + (local % h);
            n_idx = local / h;
        } else { m_idx = blockIdx.y; n_idx = blockIdx.x; }
    }
    const int m0 = m_idx * 128;
    const int n0 = n_idx * 128;
    const int wm = (wave & 1) * 64;
    const int wn = (wave >> 1) * 64;

    const int srow = lane >> 2;
    const int schk = ((lane & 3) + (lane >> 2) + (lane >> 4)) & 3;
    const int rho  = lane & 15;
    const int kap  = lane >> 4;
    const int foff = ((rho << 2) + ((kap - rho - (rho >> 2)) & 3)) * 8;   // shorts

    f32x4 acc[4][4] = {};

    const __hip_bfloat16* parts[3] = {Whi, Wmid, Wlo};
    for (int part = 0; part < 3; ++part) {
        const __hip_bfloat16* Bw = parts[part];
        for (int k0 = 0; k0 < K; k0 += 32) {
            __syncthreads();
            #pragma unroll
            for (int q = 0; q < 2; ++q) {
                int grp = wave * 2 + q;      // groups 0..7
                async16(A  + (size_t)(m0 + grp * 16 + srow) * K + k0 + schk * 8,
                        &As[grp * 512 + lane * 8]);
                async16(Bw + (size_t)(n0 + grp * 16 + srow) * K + k0 + schk * 8,
                        &Bs[grp * 512 + lane * 8]);
            }
            __syncthreads();

            bf16x8 af[4], bfr[4];
            #pragma unroll
            for (int i = 0; i < 4; ++i) {
                af[i]  = *(const bf16x8*)&As[((wm >> 4) + i) * 512 + foff];
                bfr[i] = *(const bf16x8*)&Bs[((wn >> 4) + i) * 512 + foff];
            }
            #pragma unroll
            for (int i = 0; i < 4; ++i)
                #pragma unroll
                for (int j = 0; j < 4; ++j)
                    acc[i][j] = __builtin_amdgcn_mfma_f32_16x16x32_bf16(af[i], bfr[j], acc[i][j], 0, 0, 0);
        }
    }

    #pragma unroll
    for (int i = 0; i < 4; ++i) {
        int mg = m0 + wm + i * 16 + (lane >> 4) * 4;
        #pragma unroll
        for (int j = 0; j < 4; ++j) {
            int ng = n0 + wn + j * 16 + (lane & 15);
            float bb = bias[ng];
            #pragma unroll
            for (int r = 0; r < 4; ++r)
                C[(size_t)(mg + r) * N + ng] = acc[i][j][r] + bb;
        }
    }
}

// ---------------- LIF scans — R9 verbatim ----------------
__global__ void snn_lif_bf16_v4(const float4* __restrict__ cur, ushort4* __restrict__ spk,
                                int BH4, int bcast) {
    int idx = blockIdx.x * blockDim.x + threadIdx.x;
    if (idx >= BH4) return;
    float m0 = 0.0f, m1 = 0.0f, m2 = 0.0f, m3 = 0.0f;
    const unsigned short one = __hip_bfloat16_raw(__float2bfloat16(1.0f)).x;
    if (bcast) {
        float4 c = cur[idx];
        for (int s = 0; s < S_STEPS; ++s) {
            float r0 = (m0 > 1.0f) ? 1.0f : 0.0f;
            float r1 = (m1 > 1.0f) ? 1.0f : 0.0f;
            float r2 = (m2 > 1.0f) ? 1.0f : 0.0f;
            float r3 = (m3 > 1.0f) ? 1.0f : 0.0f;
            m0 = __fsub_rn(__fadd_rn(__fmul_rn(0.9f, m0), c.x), r0);
            m1 = __fsub_rn(__fadd_rn(__fmul_rn(0.9f, m1), c.y), r1);
            m2 = __fsub_rn(__fadd_rn(__fmul_rn(0.9f, m2), c.z), r2);
            m3 = __fsub_rn(__fadd_rn(__fmul_rn(0.9f, m3), c.w), r3);
            ushort4 o;
            o.x = (m0 > 1.0f) ? one : (unsigned short)0;
            o.y = (m1 > 1.0f) ? one : (unsigned short)0;
            o.z = (m2 > 1.0f) ? one : (unsigned short)0;
            o.w = (m3 > 1.0f) ? one : (unsigned short)0;
            spk[(size_t)s * BH4 + idx] = o;
        }
    } else {
        for (int s0 = 0; s0 < S_STEPS; s0 += 4) {
            float4 c[4];
            #pragma unroll
            for (int u = 0; u < 4; ++u)
                c[u] = cur[(size_t)(s0 + u) * BH4 + idx];   // 4 loads in flight
            #pragma unroll
            for (int u = 0; u < 4; ++u) {
                float r0 = (m0 > 1.0f) ? 1.0f : 0.0f;
                float r1 = (m1 > 1.0f) ? 1.0f : 0.0f;
                float r2 = (m2 > 1.0f) ? 1.0f : 0.0f;
                float r3 = (m3 > 1.0f) ? 1.0f : 0.0f;
                m0 = __fsub_rn(__fadd_rn(__fmul_rn(0.9f, m0), c[u].x), r0);
                m1 = __fsub_rn(__fadd_rn(__fmul_rn(0.9f, m1), c[u].y), r1);
                m2 = __fsub_rn(__fadd_rn(__fmul_rn(0.9f, m2), c[u].z), r2);
                m3 = __fsub_rn(__fadd_rn(__fmul_rn(0.9f, m3), c[u].w), r3);
                ushort4 o;
                o.x = (m0 > 1.0f) ? one : (unsigned short)0;
                o.y = (m1 > 1.0f) ? one : (unsigned short)0;
                o.z = (m2 > 1.0f) ? one : (unsigned short)0;
                o.w = (m3 > 1.0f) ? one : (unsigned short)0;
                spk[(size_t)(s0 + u) * BH4 + idx] = o;
            }
        }
    }
}

__global__ void snn_lif_f32_v4(const float4* __restrict__ cur, float4* __restrict__ spk, int BH4) {
    int idx = blockIdx.x * blockDim.x + threadIdx.x;
    if (idx >= BH4) return;
    float m0 = 0.0f, m1 = 0.0f, m2 = 0.0f, m3 = 0.0f;
    for (int s0 = 0; s0 < S_STEPS; s0 += 4) {
        float4 c[4];
        #pragma unroll
        for (int u = 0; u < 4; ++u)
            c[u] = cur[(size_t)(s0 + u) * BH4 + idx];       // 4 loads in flight
        #pragma unroll
        for (int u = 0; u < 4; ++u) {
            float r0 = (m0 > 1.0f) ? 1.0f : 0.0f;
            float r1 = (m1 > 1.0f) ? 1.0f : 0.0f;
            float r2 = (m2 > 1.0f) ? 1.0f : 0.0f;
            float r3 = (m3 > 1.0f) ? 1.0f : 0.0f;
            m0 = __fsub_rn(__fadd_rn(__fmul_rn(0.9f, m0), c[u].x), r0);
            m1 = __fsub_rn(__fadd_rn(__fmul_rn(0.9f, m1), c[u].y), r1);
            m2 = __fsub_rn(__fadd_rn(__fmul_rn(0.9f, m2), c[u].z), r2);
            m3 = __fsub_rn(__fadd_rn(__fmul_rn(0.9f, m3), c[u].w), r3);
            float4 o;
            o.x = (m0 > 1.0f) ? 1.0f : 0.0f;
            o.y = (m1 > 1.0f) ? 1.0f : 0.0f;
            o.z = (m2 > 1.0f) ? 1.0f : 0.0f;
            o.w = (m3 > 1.0f) ? 1.0f : 0.0f;
            spk[(size_t)(s0 + u) * BH4 + idx] = o;
        }
    }
}

extern "C" void kernel_launch(void* const* d_in, const int* in_sizes, int n_in,
                              void* d_out, int out_size, void* d_ws, size_t ws_size,
                              hipStream_t stream) {
    const float* x  = (const float*)d_in[0];
    const float* W0 = (const float*)d_in[1];
    const float* b0 = (const float*)d_in[2];
    const float* W1 = (const float*)d_in[3];
    const float* b1 = (const float*)d_in[4];
    const float* W2 = (const float*)d_in[5];
    const float* b2 = (const float*)d_in[6];

    const int B = 256, T = 128, F = 512, H1 = 1024, H2 = 1024, H3 = 512;
    const int SB = S_STEPS * B;            // 16384

    // ---- workspace carve-up, all 16B aligned; total ~115 MB ----
    char* w = (char*)d_ws;
    __hip_bfloat16* spkA = (__hip_bfloat16*)w;              w += (size_t)SB * H1 * 2;   // 33.5 MB
    float*          curB = (float*)w;                       w += (size_t)SB * H1 * 4;   // 67 MB
    __hip_bfloat16* r_bf = (__hip_bfloat16*)w;              w += (size_t)B * F * 2;     // 256 KB
    float*          cur0 = (float*)w;                       w += (size_t)B * H1 * 4;    // 1 MB
    __hip_bfloat16* W0s  = (__hip_bfloat16*)w;              w += (size_t)3 * H1 * F * 2;
    __hip_bfloat16* W1s  = (__hip_bfloat16*)w;              w += (size_t)3 * H2 * H1 * 2;
    __hip_bfloat16* W2s  = (__hip_bfloat16*)w;              w += (size_t)3 * H3 * H2 * 2;

    const int nW0 = H1 * F, nW1 = H2 * H1, nW2 = H3 * H2;

    // batched weight splits, vec4
    {
        int n4 = (nW0 + nW1 + nW2) / 4;
        split_w3_v4<<<dim3((n4 + 255) / 256), dim3(256), 0, stream>>>(
            (const float4*)W0, (const float4*)W1, (const float4*)W2,
            nW0 / 4, nW1 / 4, nW2 / 4,
            (ushort4*)W0s, (ushort4*)W1s, (ushort4*)W2s);
    }

    // 1. delta encoder (T-parallel, 512 blocks) -> exact bf16 rates [B, F]
    snn_encoder_tp<<<dim3(F / 4 / 64, B), dim3(256), 0, stream>>>(
        (const float4*)x, (ushort4*)r_bf, B, T, F / 4);

    // 2. cur0 = r @ W0^T + b0   [256 x 1024, K=512]
    snn_gemm_mfma_n<<<dim3(H1 / 128, B / 128), dim3(256), 0, stream>>>(
        r_bf, W0s, W0s + nW0, W0s + 2 * nW0, b0, cur0, B, H1, F);

    // 3. LIF layer 0 (broadcast) -> spk0 bf16 [S, B*H1]
    snn_lif_bf16_v4<<<dim3(B * H1 / 4 / 256), dim3(256), 0, stream>>>(
        (const float4*)cur0, (ushort4*)spkA, B * H1 / 4, 1);

    // 4. cur1 = spk0 @ W1^T + b1   [16384 x 1024, K=1024]
    snn_gemm_mfma_w<<<dim3(H2 / 256, SB / 128), dim3(256), 0, stream>>>(
        spkA, W1s, W1s + nW1, W1s + 2 * nW1, b1, curB, SB, H2, H1);

    // 5. LIF layer 1 (unrolled) -> spk1 bf16 (reuse spkA)
    snn_lif_bf16_v4<<<dim3(B * H2 / 4 / 256), dim3(256), 0, stream>>>(
        (const float4*)curB, (ushort4*)spkA, B * H2 / 4, 0);

    // 6. cur2 = spk1 @ W2^T + b2   [16384 x 512, K=1024]
    snn_gemm_mfma_n<<<dim3(H3 / 128, SB / 128), dim3(256), 0, stream>>>(
        spkA, W2s, W2s + nW2, W2s + 2 * nW2, b2, curB, SB, H3, H2);

    // 7. LIF layer 2 (unrolled) -> d_out fp32 [S, B*H3]
    snn_lif_f32_v4<<<dim3(B * H3 / 4 / 256), dim3(256), 0, stream>>>(
        (const float4*)curB, (float4*)d_out, B * H3 / 4);
}